// Round 2
// baseline (94.527 us; speedup 1.0000x reference)
//
#include <hip/hip_runtime.h>

#define TPB 256
#define MAX_BLOCKS 2048

// v_sin_f32 computes sin(2*pi*x) -- input in REVOLUTIONS (cdna4_isa.md §3).
// Inputs are in [0,1]: no range reduction needed.
__device__ __forceinline__ float sin2pi(float x) {
    return __builtin_amdgcn_sinf(x);
}

// diff_round(x) = x - sin(2pi x)/(2pi): one v_sin + one v_fma
__device__ __forceinline__ float diff_round(float x) {
    return __builtin_fmaf(sin2pi(x), -0.15915494309189533577f, x);
}

// One v_add_f32_dpp: v += dpp_move(v, CTRL). Pure VALU, no LDS pipe.
template <int CTRL>
__device__ __forceinline__ float dpp_add(float v) {
    int i = __float_as_int(v);
    int m = __builtin_amdgcn_update_dpp(i, i, CTRL, 0xF, 0xF, false);
    return v + __int_as_float(m);
}

// Sum across a 16-lane DPP row: 4 VALU instructions, serial-dependent.
__device__ __forceinline__ float row_sum16(float s) {
    s = dpp_add<0xB1>(s);   // quad_perm [1,0,3,2]  == xor 1
    s = dpp_add<0x4E>(s);   // quad_perm [2,3,0,1]  == xor 2
    s = dpp_add<0x124>(s);  // row_ror:4
    s = dpp_add<0x128>(s);  // row_ror:8
    return s;
}

// R7: single-round algebra. varr = sum((x - mean)^2 m^2)/msum expands to
//   (A - 2 mean B + mean^2 C)/msum,  x = img*m, u = x*m,
//   A = sum u^2, B = sum u*m, C = sum m^2, mean = Sx/msum, msum = S1 + eps.
// All FIVE sums are independent -> one reduction round (5 interleaved DPP
// chains) instead of two dependent rounds + a dev re-pass. Shorter critical
// path, fewer live temps.
struct Sums { float s1, sx, a, b, c; };

__device__ __forceinline__ void accum(Sums& s, float i, float mraw) {
    const float m = diff_round(diff_round(mraw));
    const float x = i * m;
    const float u = x * m;
    s.s1 += m;
    s.sx += x;
    s.a = __builtin_fmaf(u, u, s.a);
    s.b = __builtin_fmaf(u, m, s.b);
    s.c = __builtin_fmaf(m, m, s.c);
}

// varr for one tile; result uniform across the 16-lane row.
__device__ __forceinline__ float tile_varr(const float4 iv, const float4 mv) {
    Sums s = {0.f, 0.f, 0.f, 0.f, 0.f};
    accum(s, iv.x, mv.x);
    accum(s, iv.y, mv.y);
    accum(s, iv.z, mv.z);
    accum(s, iv.w, mv.w);
    const float S1 = row_sum16(s.s1);
    const float Sx = row_sum16(s.sx);
    const float A  = row_sum16(s.a);
    const float B  = row_sum16(s.b);
    const float C  = row_sum16(s.c);
    const float r    = __builtin_amdgcn_rcpf(S1 + 1e-8f);  // ~1 ulp, thr 1.5e-2
    const float mean = Sx * r;
    // A - mean*(2B - mean*C) == A - 2*mean*B + mean^2*C  (two fmas)
    return __builtin_fmaf(-mean, __builtin_fmaf(-mean, C, 2.0f * B), A) * r;
}

// R7: software prefetch REMOVED. The R6 prefetch kept 8 float4 buffers +
// duplicated address chains live -> VGPR pressure -> ~2 waves/SIMD -> too few
// loads in flight (latency-bound at ~1.7 TB/s). Fix is occupancy, not ILP:
// __launch_bounds__(TPB, 8) caps at 64 VGPR -> 8 waves/SIMD -> 8192 resident
// waves whose natural TLP keeps >>2.4 MB in flight (Little's law for 6.3 TB/s
// at ~375 ns HBM latency). Each 16-lane row still handles TWO adjacent tiles
// per iteration for intra-wave ILP on the sin/DPP chains (cheap now: the
// 5-sum algebra keeps lifetimes short).
__global__ __launch_bounds__(TPB, 8) void area_var_partial(
    const float* __restrict__ img, const float* __restrict__ msk,
    float* __restrict__ partial, int ntiles) {
    const int tid  = threadIdx.x;
    const int wave = tid >> 6;      // 0..3
    const int lane = tid & 63;
    const int grp  = lane >> 4;     // DPP row within wave
    const int j    = lane & 15;     // float4 index within tile

    const int tiles_per_block = (TPB / 64) * 4 * 2;  // 32
    const int stride = gridDim.x * tiles_per_block;
    float acc = 0.0f;               // row-uniform

    for (int t0 = blockIdx.x * tiles_per_block + (wave * 4 + grp) * 2;
         t0 < ntiles; t0 += stride) {
        const size_t off = (size_t)t0 * 64 + (size_t)j * 4;
        const float4 ivA = *reinterpret_cast<const float4*>(img + off);
        const float4 mvA = *reinterpret_cast<const float4*>(msk + off);
        float4 ivB = make_float4(0.f, 0.f, 0.f, 0.f);
        float4 mvB = make_float4(0.f, 0.f, 0.f, 0.f);
        if (t0 + 1 < ntiles) {      // tile B = t0+1, 256 bytes further
            ivB = *reinterpret_cast<const float4*>(img + off + 64);
            mvB = *reinterpret_cast<const float4*>(msk + off + 64);
        }
        acc += tile_varr(ivA, mvA);   // two independent chains --
        acc += tile_varr(ivB, mvB);   // scheduler interleaves them
    }

    // acc uniform per row; sum the wave's 4 rows, then the block's 4 waves.
    acc += __shfl_xor(acc, 16, 64);
    acc += __shfl_xor(acc, 32, 64);

    __shared__ float wsum[TPB / 64];
    if (lane == 0) wsum[wave] = acc;
    __syncthreads();
    if (tid == 0) partial[blockIdx.x] = (wsum[0] + wsum[1]) + (wsum[2] + wsum[3]);
}

__global__ __launch_bounds__(TPB) void final_reduce(
    const float* __restrict__ partial, float* __restrict__ out,
    int n, float inv_count) {
    float s = 0.f;
    for (int i = threadIdx.x; i < n; i += TPB) s += partial[i];
    #pragma unroll
    for (int d = 1; d < 64; d <<= 1) s += __shfl_xor(s, d, 64);
    __shared__ float wsum[TPB / 64];
    const int wave = threadIdx.x >> 6;
    const int lane = threadIdx.x & 63;
    if (lane == 0) wsum[wave] = s;
    __syncthreads();
    if (threadIdx.x == 0)
        out[0] = ((wsum[0] + wsum[1]) + (wsum[2] + wsum[3])) * inv_count;
}

extern "C" void kernel_launch(void* const* d_in, const int* in_sizes, int n_in,
                              void* d_out, int out_size, void* d_ws, size_t ws_size,
                              hipStream_t stream) {
    const float* img = (const float*)d_in[0];   // sv_area_image [B,N,P,Q] fp32
    const float* msk = (const float*)d_in[1];   // sv_area_mask  [B,N,P,Q] fp32
    float* out = (float*)d_out;                 // scalar fp32
    float* partial = (float*)d_ws;

    const int ntiles = in_sizes[0] / 64;        // B*N = 131072
    int nblocks = (ntiles + 31) / 32;
    if (nblocks > MAX_BLOCKS) nblocks = MAX_BLOCKS;  // 2048 -> exactly 2 iters

    area_var_partial<<<nblocks, TPB, 0, stream>>>(img, msk, partial, ntiles);
    final_reduce<<<1, TPB, 0, stream>>>(partial, out, nblocks,
                                        1.0f / (float)ntiles);
}